// Round 1
// baseline (2151.062 us; speedup 1.0000x reference)
//
#include <hip/hip_runtime.h>

#define N_NODES 100000
#define N_EDGES 3200000
#define N_GRAPHS 2048
#define DIM 32
#define FEAT 78
#define OUT_DIM 128
#define BN_EPS 1e-5f

// ---------------- CSR build ----------------
__global__ void hist_kernel(const int* __restrict__ dst, int* __restrict__ counts) {
    int i = blockIdx.x * blockDim.x + threadIdx.x;
    int stride = gridDim.x * blockDim.x;
    for (; i < N_EDGES; i += stride)
        atomicAdd(&counts[dst[i]], 1);
}

__global__ __launch_bounds__(1024) void scan_kernel(const int* __restrict__ counts,
                                                    int* __restrict__ row_start,
                                                    int* __restrict__ cursor) {
    __shared__ int part[1024];
    int tid = threadIdx.x;
    const int chunk = (N_NODES + 1023) / 1024;  // 98
    int start = tid * chunk;
    int end = start + chunk; if (end > N_NODES) end = N_NODES;
    int s = 0;
    for (int i = start; i < end; ++i) s += counts[i];
    part[tid] = s;
    __syncthreads();
    for (int off = 1; off < 1024; off <<= 1) {
        int v = 0;
        if (tid >= off) v = part[tid - off];
        __syncthreads();
        part[tid] += v;
        __syncthreads();
    }
    int run = part[tid] - s;  // exclusive prefix of this chunk
    for (int i = start; i < end; ++i) {
        row_start[i] = run;
        cursor[i] = run;
        run += counts[i];
    }
    if (tid == 1023) row_start[N_NODES] = part[1023];
}

__global__ void fill_kernel(const int* __restrict__ src, const int* __restrict__ dst,
                            int* __restrict__ cursor, int* __restrict__ csr) {
    int i = blockIdx.x * blockDim.x + threadIdx.x;
    int stride = gridDim.x * blockDim.x;
    for (; i < N_EDGES; i += stride) {
        int d = dst[i];
        int pos = atomicAdd(&cursor[d], 1);
        csr[pos] = src[i];
    }
}

// ---------------- t = x @ W1a  (78 -> 32) ----------------
__global__ __launch_bounds__(256) void transform1_kernel(const float* __restrict__ x,
                                                         const float* __restrict__ W,
                                                         float* __restrict__ t) {
    __shared__ float Wl[FEAT * DIM];
    for (int i = threadIdx.x; i < FEAT * DIM; i += blockDim.x) Wl[i] = W[i];
    __syncthreads();
    int lane = threadIdx.x & 31;
    int group = threadIdx.x >> 5;
    int gpb = blockDim.x >> 5;
    for (int node = blockIdx.x * gpb + group; node < N_NODES; node += gridDim.x * gpb) {
        const float* xr = x + (size_t)node * FEAT;
        float acc = 0.f;
        for (int k = 0; k < FEAT; ++k)
            acc += xr[k] * Wl[k * DIM + lane];
        t[node * DIM + lane] = acc;
    }
}

// ---------------- agg (gather) + bias + relu + @Wb + bias + relu + BN stats ----------------
__global__ __launch_bounds__(256) void agg_mlp_kernel(const float* __restrict__ t,
                                                      const int* __restrict__ row_start,
                                                      const int* __restrict__ csr,
                                                      const float* __restrict__ bias_a,
                                                      const float* __restrict__ Wb,
                                                      const float* __restrict__ bias_b,
                                                      float* __restrict__ h_out,
                                                      float* __restrict__ stats) {
    __shared__ float Wl[DIM * DIM];
    __shared__ float lsum[DIM], lsumsq[DIM];
    for (int i = threadIdx.x; i < DIM * DIM; i += blockDim.x) Wl[i] = Wb[i];
    if (threadIdx.x < DIM) { lsum[threadIdx.x] = 0.f; lsumsq[threadIdx.x] = 0.f; }
    __syncthreads();
    int lane = threadIdx.x & 31;
    int group = threadIdx.x >> 5;
    int gpb = blockDim.x >> 5;
    float ba = bias_a[lane], bbv = bias_b[lane];
    float ls = 0.f, lss = 0.f;
    for (int node = blockIdx.x * gpb + group; node < N_NODES; node += gridDim.x * gpb) {
        int rs = row_start[node], re = row_start[node + 1];
        float acc = t[node * DIM + lane];
        for (int p = rs; p < re; ++p) {
            int s = csr[p];
            acc += t[s * DIM + lane];
        }
        acc = fmaxf(acc + ba, 0.f);
        float y = bbv;
        #pragma unroll
        for (int k = 0; k < DIM; ++k)
            y += __shfl(acc, k, 32) * Wl[k * DIM + lane];
        y = fmaxf(y, 0.f);
        h_out[node * DIM + lane] = y;
        ls += y;
        lss += y * y;
    }
    // combine the two 32-lane halves of each 64-wide wave
    ls  += __shfl_xor(ls, 32);
    lss += __shfl_xor(lss, 32);
    if ((threadIdx.x & 63) < 32) {
        atomicAdd(&lsum[lane], ls);
        atomicAdd(&lsumsq[lane], lss);
    }
    __syncthreads();
    if (threadIdx.x < DIM) {
        atomicAdd(&stats[threadIdx.x], lsum[threadIdx.x]);
        atomicAdd(&stats[DIM + threadIdx.x], lsumsq[threadIdx.x]);
    }
}

// ---------------- BN normalize + t = hnorm @ Wa (for next layer) ----------------
__global__ __launch_bounds__(256) void bn_transform_kernel(const float* __restrict__ h,
                                                           const float* __restrict__ stats,
                                                           const float* __restrict__ gamma,
                                                           const float* __restrict__ beta,
                                                           const float* __restrict__ Wa,
                                                           float* __restrict__ t) {
    __shared__ float Wl[DIM * DIM];
    for (int i = threadIdx.x; i < DIM * DIM; i += blockDim.x) Wl[i] = Wa[i];
    __syncthreads();
    int lane = threadIdx.x & 31;
    int group = threadIdx.x >> 5;
    int gpb = blockDim.x >> 5;
    float mu = stats[lane] * (1.f / N_NODES);
    float var = stats[DIM + lane] * (1.f / N_NODES) - mu * mu;
    float inv = rsqrtf(var + BN_EPS);
    float a = gamma[lane] * inv;
    float c = beta[lane] - mu * a;
    for (int node = blockIdx.x * gpb + group; node < N_NODES; node += gridDim.x * gpb) {
        float v = h[node * DIM + lane] * a + c;
        float y = 0.f;
        #pragma unroll
        for (int k = 0; k < DIM; ++k)
            y += __shfl(v, k, 32) * Wl[k * DIM + lane];
        t[node * DIM + lane] = y;
    }
}

// ---------------- final BN + global_add_pool ----------------
__global__ __launch_bounds__(256) void bn_pool_kernel(const float* __restrict__ h,
                                                      const float* __restrict__ stats,
                                                      const float* __restrict__ gamma,
                                                      const float* __restrict__ beta,
                                                      const int* __restrict__ batch,
                                                      float* __restrict__ pooled) {
    int lane = threadIdx.x & 31;
    int group = threadIdx.x >> 5;
    int gpb = blockDim.x >> 5;
    float mu = stats[lane] * (1.f / N_NODES);
    float var = stats[DIM + lane] * (1.f / N_NODES) - mu * mu;
    float inv = rsqrtf(var + BN_EPS);
    float a = gamma[lane] * inv;
    float c = beta[lane] - mu * a;
    for (int node = blockIdx.x * gpb + group; node < N_NODES; node += gridDim.x * gpb) {
        float v = h[node * DIM + lane] * a + c;
        int g = batch[node];
        atomicAdd(&pooled[g * DIM + lane], v);
    }
}

// ---------------- out = relu(pooled @ Wfc + bfc) ----------------
__global__ __launch_bounds__(256) void fc_kernel(const float* __restrict__ pooled,
                                                 const float* __restrict__ Wfc,
                                                 const float* __restrict__ bfc,
                                                 float* __restrict__ out) {
    __shared__ float Wl[DIM * OUT_DIM];
    for (int i = threadIdx.x; i < DIM * OUT_DIM; i += blockDim.x) Wl[i] = Wfc[i];
    __syncthreads();
    int idx = blockIdx.x * blockDim.x + threadIdx.x;
    int stride = gridDim.x * blockDim.x;
    for (; idx < N_GRAPHS * OUT_DIM; idx += stride) {
        int g = idx >> 7;
        int o = idx & 127;
        float acc = bfc[o];
        #pragma unroll
        for (int k = 0; k < DIM; ++k)
            acc += pooled[g * DIM + k] * Wl[k * OUT_DIM + o];
        out[idx] = fmaxf(acc, 0.f);
    }
}

extern "C" void kernel_launch(void* const* d_in, const int* in_sizes, int n_in,
                              void* d_out, int out_size, void* d_ws, size_t ws_size,
                              hipStream_t stream) {
    const float* x   = (const float*)d_in[0];
    const int* eidx  = (const int*)d_in[1];
    const int* src   = eidx;
    const int* dst   = eidx + N_EDGES;
    const int* batch = (const int*)d_in[2];
    const float* W1a = (const float*)d_in[3];
    const float* b1a = (const float*)d_in[4];
    const float* W1b = (const float*)d_in[5];
    const float* b1b = (const float*)d_in[6];
    const float* Wa  = (const float*)d_in[7];
    const float* ba  = (const float*)d_in[8];
    const float* Wb  = (const float*)d_in[9];
    const float* bb  = (const float*)d_in[10];
    const float* gamma = (const float*)d_in[11];
    const float* beta  = (const float*)d_in[12];
    const float* Wfc = (const float*)d_in[13];
    const float* bfc = (const float*)d_in[14];
    float* out = (float*)d_out;

    float* wsf    = (float*)d_ws;
    float* t      = wsf;
    float* hbuf   = t + (size_t)N_NODES * DIM;
    float* stats  = hbuf + (size_t)N_NODES * DIM;   // 5 layers * 64
    float* pooled = stats + 5 * 64;
    int* counts   = (int*)(pooled + N_GRAPHS * DIM);
    int* rowst    = counts + N_NODES;
    int* cursor   = rowst + N_NODES + 1;
    int* csr      = cursor + N_NODES;

    hipMemsetAsync(counts, 0, N_NODES * sizeof(int), stream);
    hipMemsetAsync(stats, 0, 5 * 64 * sizeof(float), stream);
    hipMemsetAsync(pooled, 0, N_GRAPHS * DIM * sizeof(float), stream);

    hist_kernel<<<2048, 256, 0, stream>>>(dst, counts);
    scan_kernel<<<1, 1024, 0, stream>>>(counts, rowst, cursor);
    fill_kernel<<<2048, 256, 0, stream>>>(src, dst, cursor, csr);

    transform1_kernel<<<2048, 256, 0, stream>>>(x, W1a, t);
    agg_mlp_kernel<<<2048, 256, 0, stream>>>(t, rowst, csr, b1a, W1b, b1b, hbuf, stats + 0);
    for (int i = 0; i < 4; ++i) {
        bn_transform_kernel<<<2048, 256, 0, stream>>>(hbuf, stats + i * 64,
                                                      gamma + i * DIM, beta + i * DIM,
                                                      Wa + i * DIM * DIM, t);
        agg_mlp_kernel<<<2048, 256, 0, stream>>>(t, rowst, csr, ba + i * DIM,
                                                 Wb + i * DIM * DIM, bb + i * DIM,
                                                 hbuf, stats + (i + 1) * 64);
    }
    bn_pool_kernel<<<2048, 256, 0, stream>>>(hbuf, stats + 4 * 64,
                                             gamma + 4 * DIM, beta + 4 * DIM, batch, pooled);
    fc_kernel<<<1024, 256, 0, stream>>>(pooled, Wfc, bfc, out);
}

// Round 2
// 916.756 us; speedup vs baseline: 2.3464x; 2.3464x over previous
//
#include <hip/hip_runtime.h>

#define N_NODES 100000
#define N_EDGES 3200000
#define N_GRAPHS 2048
#define DIM 32
#define FEAT 78
#define OUT_DIM 128
#define BN_EPS 1e-5f

#define BSHIFT 9
#define BSIZE 512                      // nodes per bucket
#define NB ((N_NODES + BSIZE - 1) / BSIZE)   // 196 buckets
#define CHUNK 8192                     // edges per scatter block

// ---------------- K1: coarse bucket histogram ----------------
__global__ __launch_bounds__(256) void bucket_hist_kernel(const int* __restrict__ dst,
                                                          int* __restrict__ bcnt) {
    __shared__ int lh[256];
    int tid = threadIdx.x;
    lh[tid] = 0;
    __syncthreads();
    int i = blockIdx.x * blockDim.x + tid;
    int stride = gridDim.x * blockDim.x;
    for (; i < N_EDGES; i += stride)
        atomicAdd(&lh[dst[i] >> BSHIFT], 1);
    __syncthreads();
    if (tid < NB && lh[tid])
        atomicAdd(&bcnt[tid], lh[tid]);
}

// ---------------- K2: scan over buckets ----------------
__global__ __launch_bounds__(256) void bucket_scan_kernel(const int* __restrict__ bcnt,
                                                          int* __restrict__ bstart,
                                                          int* __restrict__ bcursor,
                                                          int* __restrict__ rowst) {
    __shared__ int sc[256];
    int tid = threadIdx.x;
    int v = (tid < NB) ? bcnt[tid] : 0;
    sc[tid] = v;
    __syncthreads();
    for (int off = 1; off < 256; off <<= 1) {
        int nv = (tid >= off) ? sc[tid - off] : 0;
        __syncthreads();
        sc[tid] += nv;
        __syncthreads();
    }
    if (tid < NB) {
        int ex = sc[tid] - v;
        bstart[tid] = ex;
        bcursor[tid] = ex;
    }
    if (tid == 0) {
        bstart[NB] = N_EDGES;
        rowst[N_NODES] = N_EDGES;
    }
}

// ---------------- K3: multisplit scatter into bucket segments ----------------
__global__ __launch_bounds__(256) void bucket_scatter_kernel(const int* __restrict__ src,
                                                             const int* __restrict__ dst,
                                                             int* __restrict__ bcursor,
                                                             int* __restrict__ bsrc,
                                                             unsigned short* __restrict__ blow) {
    __shared__ int lsrc[CHUNK];
    __shared__ int ldst[CHUNK];
    __shared__ int lhist[256];
    __shared__ int sc[256];
    __shared__ int lpre[256];
    __shared__ int gbase[256];
    __shared__ int lcur[256];
    int tid = threadIdx.x;
    int base = blockIdx.x * CHUNK;
    int n = N_EDGES - base; if (n > CHUNK) n = CHUNK;

    lhist[tid] = 0;
    __syncthreads();
    for (int i = tid; i < n; i += 256)
        atomicAdd(&lhist[dst[base + i] >> BSHIFT], 1);
    __syncthreads();
    int v = lhist[tid];
    sc[tid] = v;
    __syncthreads();
    for (int off = 1; off < 256; off <<= 1) {
        int nv = (tid >= off) ? sc[tid - off] : 0;
        __syncthreads();
        sc[tid] += nv;
        __syncthreads();
    }
    int ex = sc[tid] - v;
    lpre[tid] = ex;
    lcur[tid] = ex;
    if (tid < NB && v)
        gbase[tid] = atomicAdd(&bcursor[tid], v);
    __syncthreads();
    // local scatter (bucket-ordered) into LDS
    for (int i = tid; i < n; i += 256) {
        int d = dst[base + i];
        int s = src[base + i];
        int b = d >> BSHIFT;
        int pos = atomicAdd(&lcur[b], 1);
        lsrc[pos] = s;
        ldst[pos] = d;
    }
    __syncthreads();
    // coalesced flush
    for (int i = tid; i < n; i += 256) {
        int d = ldst[i];
        int b = d >> BSHIFT;
        int gpos = gbase[b] + (i - lpre[b]);
        bsrc[gpos] = lsrc[i];
        blow[gpos] = (unsigned short)(d & (BSIZE - 1));
    }
}

// ---------------- K4: per-bucket counting sort -> csr + rowst ----------------
__global__ __launch_bounds__(256) void node_sort_kernel(const int* __restrict__ bstart,
                                                        const int* __restrict__ bsrc,
                                                        const unsigned short* __restrict__ blow,
                                                        int* __restrict__ csr,
                                                        int* __restrict__ rowst) {
    __shared__ int lcnt[BSIZE];
    __shared__ int sc[256];
    __shared__ int lpre[BSIZE];
    __shared__ int lcur[BSIZE];
    int tid = threadIdx.x;
    int b = blockIdx.x;
    int ss = bstart[b], se = bstart[b + 1];
    lcnt[tid] = 0; lcnt[tid + 256] = 0;
    __syncthreads();
    for (int i = ss + tid; i < se; i += 256)
        atomicAdd(&lcnt[blow[i]], 1);
    __syncthreads();
    int a0 = lcnt[2 * tid], a1 = lcnt[2 * tid + 1];
    int s = a0 + a1;
    sc[tid] = s;
    __syncthreads();
    for (int off = 1; off < 256; off <<= 1) {
        int nv = (tid >= off) ? sc[tid - off] : 0;
        __syncthreads();
        sc[tid] += nv;
        __syncthreads();
    }
    int ex = sc[tid] - s;
    lpre[2 * tid] = ex;
    lpre[2 * tid + 1] = ex + a0;
    lcur[2 * tid] = ex;
    lcur[2 * tid + 1] = ex + a0;
    __syncthreads();
    int node_base = b << BSHIFT;
    for (int j = tid; j < BSIZE; j += 256) {
        int node = node_base + j;
        if (node < N_NODES) rowst[node] = ss + lpre[j];
    }
    for (int i = ss + tid; i < se; i += 256) {
        int nloc = blow[i];
        int pos = atomicAdd(&lcur[nloc], 1);
        csr[ss + pos] = bsrc[i];
    }
}

// ---------------- t = x @ W1a  (78 -> 32) ----------------
__global__ __launch_bounds__(256) void transform1_kernel(const float* __restrict__ x,
                                                         const float* __restrict__ W,
                                                         float* __restrict__ t) {
    __shared__ float Wl[FEAT * DIM];
    for (int i = threadIdx.x; i < FEAT * DIM; i += blockDim.x) Wl[i] = W[i];
    __syncthreads();
    int lane = threadIdx.x & 31;
    int group = threadIdx.x >> 5;
    int gpb = blockDim.x >> 5;
    for (int node = blockIdx.x * gpb + group; node < N_NODES; node += gridDim.x * gpb) {
        const float* xr = x + (size_t)node * FEAT;
        float r0 = xr[lane];
        float r1 = xr[32 + lane];
        float r2 = (lane < FEAT - 64) ? xr[64 + lane] : 0.f;
        float acc = 0.f;
        #pragma unroll
        for (int k = 0; k < 32; ++k)
            acc += __shfl(r0, k, 32) * Wl[k * DIM + lane];
        #pragma unroll
        for (int k = 0; k < 32; ++k)
            acc += __shfl(r1, k, 32) * Wl[(32 + k) * DIM + lane];
        #pragma unroll
        for (int k = 0; k < FEAT - 64; ++k)
            acc += __shfl(r2, k, 32) * Wl[(64 + k) * DIM + lane];
        t[node * DIM + lane] = acc;
    }
}

// ---------------- agg (gather) + bias + relu + @Wb + bias + relu + BN stats ----------------
__global__ __launch_bounds__(256) void agg_mlp_kernel(const float* __restrict__ t,
                                                      const int* __restrict__ row_start,
                                                      const int* __restrict__ csr,
                                                      const float* __restrict__ bias_a,
                                                      const float* __restrict__ Wb,
                                                      const float* __restrict__ bias_b,
                                                      float* __restrict__ h_out,
                                                      float* __restrict__ stats) {
    __shared__ float Wl[DIM * DIM];
    __shared__ float lsum[DIM], lsumsq[DIM];
    for (int i = threadIdx.x; i < DIM * DIM; i += blockDim.x) Wl[i] = Wb[i];
    if (threadIdx.x < DIM) { lsum[threadIdx.x] = 0.f; lsumsq[threadIdx.x] = 0.f; }
    __syncthreads();
    int lane = threadIdx.x & 31;
    int group = threadIdx.x >> 5;
    int gpb = blockDim.x >> 5;
    const float* tl = t + lane;
    float ba = bias_a[lane], bbv = bias_b[lane];
    float ls = 0.f, lss = 0.f;
    for (int node = blockIdx.x * gpb + group; node < N_NODES; node += gridDim.x * gpb) {
        int rs = row_start[node], re = row_start[node + 1];
        float acc = tl[node * DIM];
        int p = rs;
        for (; p + 4 <= re; p += 4) {
            int s0 = csr[p], s1 = csr[p + 1], s2 = csr[p + 2], s3 = csr[p + 3];
            float v0 = tl[s0 * DIM];
            float v1 = tl[s1 * DIM];
            float v2 = tl[s2 * DIM];
            float v3 = tl[s3 * DIM];
            acc += (v0 + v1) + (v2 + v3);
        }
        for (; p < re; ++p)
            acc += tl[csr[p] * DIM];
        acc = fmaxf(acc + ba, 0.f);
        float y = bbv;
        #pragma unroll
        for (int k = 0; k < DIM; ++k)
            y += __shfl(acc, k, 32) * Wl[k * DIM + lane];
        y = fmaxf(y, 0.f);
        h_out[node * DIM + lane] = y;
        ls += y;
        lss += y * y;
    }
    ls  += __shfl_xor(ls, 32);
    lss += __shfl_xor(lss, 32);
    if ((threadIdx.x & 63) < 32) {
        atomicAdd(&lsum[lane], ls);
        atomicAdd(&lsumsq[lane], lss);
    }
    __syncthreads();
    if (threadIdx.x < DIM) {
        atomicAdd(&stats[threadIdx.x], lsum[threadIdx.x]);
        atomicAdd(&stats[DIM + threadIdx.x], lsumsq[threadIdx.x]);
    }
}

// ---------------- BN normalize + t = hnorm @ Wa (for next layer) ----------------
__global__ __launch_bounds__(256) void bn_transform_kernel(const float* __restrict__ h,
                                                           const float* __restrict__ stats,
                                                           const float* __restrict__ gamma,
                                                           const float* __restrict__ beta,
                                                           const float* __restrict__ Wa,
                                                           float* __restrict__ t) {
    __shared__ float Wl[DIM * DIM];
    for (int i = threadIdx.x; i < DIM * DIM; i += blockDim.x) Wl[i] = Wa[i];
    __syncthreads();
    int lane = threadIdx.x & 31;
    int group = threadIdx.x >> 5;
    int gpb = blockDim.x >> 5;
    float mu = stats[lane] * (1.f / N_NODES);
    float var = stats[DIM + lane] * (1.f / N_NODES) - mu * mu;
    float inv = rsqrtf(var + BN_EPS);
    float a = gamma[lane] * inv;
    float c = beta[lane] - mu * a;
    for (int node = blockIdx.x * gpb + group; node < N_NODES; node += gridDim.x * gpb) {
        float v = h[node * DIM + lane] * a + c;
        float y = 0.f;
        #pragma unroll
        for (int k = 0; k < DIM; ++k)
            y += __shfl(v, k, 32) * Wl[k * DIM + lane];
        t[node * DIM + lane] = y;
    }
}

// ---------------- final BN + global_add_pool (run-length compressed, batch sorted) ----------------
#define POOL_BLOCKS 512
__global__ __launch_bounds__(256) void bn_pool_kernel(const float* __restrict__ h,
                                                      const float* __restrict__ stats,
                                                      const float* __restrict__ gamma,
                                                      const float* __restrict__ beta,
                                                      const int* __restrict__ batch,
                                                      float* __restrict__ pooled) {
    int lane = threadIdx.x & 31;
    int group = threadIdx.x >> 5;
    float mu = stats[lane] * (1.f / N_NODES);
    float var = stats[DIM + lane] * (1.f / N_NODES) - mu * mu;
    float inv = rsqrtf(var + BN_EPS);
    float a = gamma[lane] * inv;
    float c = beta[lane] - mu * a;
    const int ngroups = POOL_BLOCKS * 8;
    const int chunk = (N_NODES + ngroups - 1) / ngroups;
    int g = blockIdx.x * 8 + group;
    int start = g * chunk;
    if (start >= N_NODES) return;
    int end = start + chunk; if (end > N_NODES) end = N_NODES;
    int cur = batch[start];
    float s = 0.f;
    for (int node = start; node < end; ++node) {
        float v = h[node * DIM + lane] * a + c;
        int bg = batch[node];
        if (bg != cur) {
            atomicAdd(&pooled[cur * DIM + lane], s);
            s = 0.f;
            cur = bg;
        }
        s += v;
    }
    atomicAdd(&pooled[cur * DIM + lane], s);
}

// ---------------- out = relu(pooled @ Wfc + bfc) ----------------
__global__ __launch_bounds__(256) void fc_kernel(const float* __restrict__ pooled,
                                                 const float* __restrict__ Wfc,
                                                 const float* __restrict__ bfc,
                                                 float* __restrict__ out) {
    __shared__ float Wl[DIM * OUT_DIM];
    for (int i = threadIdx.x; i < DIM * OUT_DIM; i += blockDim.x) Wl[i] = Wfc[i];
    __syncthreads();
    int idx = blockIdx.x * blockDim.x + threadIdx.x;
    int stride = gridDim.x * blockDim.x;
    for (; idx < N_GRAPHS * OUT_DIM; idx += stride) {
        int g = idx >> 7;
        int o = idx & 127;
        float acc = bfc[o];
        #pragma unroll
        for (int k = 0; k < DIM; ++k)
            acc += pooled[g * DIM + k] * Wl[k * OUT_DIM + o];
        out[idx] = fmaxf(acc, 0.f);
    }
}

extern "C" void kernel_launch(void* const* d_in, const int* in_sizes, int n_in,
                              void* d_out, int out_size, void* d_ws, size_t ws_size,
                              hipStream_t stream) {
    const float* x   = (const float*)d_in[0];
    const int* eidx  = (const int*)d_in[1];
    const int* src   = eidx;
    const int* dst   = eidx + N_EDGES;
    const int* batch = (const int*)d_in[2];
    const float* W1a = (const float*)d_in[3];
    const float* b1a = (const float*)d_in[4];
    const float* W1b = (const float*)d_in[5];
    const float* b1b = (const float*)d_in[6];
    const float* Wa  = (const float*)d_in[7];
    const float* ba  = (const float*)d_in[8];
    const float* Wb  = (const float*)d_in[9];
    const float* bb  = (const float*)d_in[10];
    const float* gamma = (const float*)d_in[11];
    const float* beta  = (const float*)d_in[12];
    const float* Wfc = (const float*)d_in[13];
    const float* bfc = (const float*)d_in[14];
    float* out = (float*)d_out;

    float* wsf    = (float*)d_ws;
    float* t      = wsf;                                 // 3.2M floats
    float* hbuf   = t + (size_t)N_NODES * DIM;           // 3.2M floats
    float* stats  = hbuf + (size_t)N_NODES * DIM;        // 5 * 64
    float* pooled = stats + 5 * 64;                      // 65536
    int* csr      = (int*)(pooled + N_GRAPHS * DIM);     // 3.2M
    int* rowst    = csr + N_EDGES;                       // N_NODES+1
    int* bcnt     = rowst + N_NODES + 1;                 // 256
    int* bstart   = bcnt + 256;                          // NB+1
    int* bcursor  = bstart + NB + 1;                     // 256

    // bucket pair arrays alias t/h (dead until transform1)
    int* bsrc           = (int*)t;
    unsigned short* blow = (unsigned short*)hbuf;

    hipMemsetAsync(bcnt, 0, 256 * sizeof(int), stream);
    hipMemsetAsync(stats, 0, 5 * 64 * sizeof(float), stream);
    hipMemsetAsync(pooled, 0, N_GRAPHS * DIM * sizeof(float), stream);

    bucket_hist_kernel<<<1024, 256, 0, stream>>>(dst, bcnt);
    bucket_scan_kernel<<<1, 256, 0, stream>>>(bcnt, bstart, bcursor, rowst);
    bucket_scatter_kernel<<<(N_EDGES + CHUNK - 1) / CHUNK, 256, 0, stream>>>(src, dst, bcursor, bsrc, blow);
    node_sort_kernel<<<NB, 256, 0, stream>>>(bstart, bsrc, blow, csr, rowst);

    transform1_kernel<<<2048, 256, 0, stream>>>(x, W1a, t);
    agg_mlp_kernel<<<2048, 256, 0, stream>>>(t, rowst, csr, b1a, W1b, b1b, hbuf, stats + 0);
    for (int i = 0; i < 4; ++i) {
        bn_transform_kernel<<<2048, 256, 0, stream>>>(hbuf, stats + i * 64,
                                                      gamma + i * DIM, beta + i * DIM,
                                                      Wa + i * DIM * DIM, t);
        agg_mlp_kernel<<<2048, 256, 0, stream>>>(t, rowst, csr, ba + i * DIM,
                                                 Wb + i * DIM * DIM, bb + i * DIM,
                                                 hbuf, stats + (i + 1) * 64);
    }
    bn_pool_kernel<<<POOL_BLOCKS, 256, 0, stream>>>(hbuf, stats + 4 * 64,
                                                    gamma + 4 * DIM, beta + 4 * DIM, batch, pooled);
    fc_kernel<<<1024, 256, 0, stream>>>(pooled, Wfc, bfc, out);
}